// Round 7
// baseline (49.196 us; speedup 1.0000x reference)
//
#include <hip/hip_runtime.h>

#define G 512

typedef float  v2f __attribute__((ext_vector_type(2)));
typedef float  v4f __attribute__((ext_vector_type(4)));
typedef int    v4i __attribute__((ext_vector_type(4)));
typedef unsigned int v4u __attribute__((ext_vector_type(4)));

// ---- fp4 e2m1 quantizer (round-to-nearest): |v| -> code 0..7, +8 for sign ----
// values: 0, 0.5, 1, 1.5, 2, 3, 4, 6 ; boundaries at 0.25,0.75,1.25,1.75,2.5,3.5,5
__device__ __forceinline__ unsigned int q_e2m1(float v) {
    float a = fabsf(v);
    unsigned int c = 0;
    c += (a >= 0.25f); c += (a >= 0.75f); c += (a >= 1.25f);
    c += (a >= 1.75f); c += (a >= 2.5f);  c += (a >= 3.5f);
    c += (a >= 5.0f);
    return c | (v < 0.0f ? 8u : 0u);
}

// ---------------- pack kernel ----------------
// Entry (a,b) = full 4x4x2 neighborhood rows a..a+3, cols b..b+3 as 32 fp4 = 16B.
// dword[col] byte[row]: low nibble = x, high nibble = y.
// Also zeroes the output scalar (ordered before main kernel on the stream).
__global__ __launch_bounds__(256) void pack_kernel(const float2* __restrict__ CP,
                                                   v4u* __restrict__ P,
                                                   float* __restrict__ out) {
    const int t = blockIdx.x * 256 + (int)threadIdx.x;  // [0, G*G)
    if (t == 0) *out = 0.0f;
    const int a = t >> 9;          // anchor row
    const int b = t & (G - 1);     // anchor col
    unsigned int d[4];
    #pragma unroll
    for (int col = 0; col < 4; ++col) {
        unsigned int dw = 0;
        #pragma unroll
        for (int row = 0; row < 4; ++row) {
            float2 v = CP[(size_t)min(a + row, G - 1) * G + min(b + col, G - 1)];
            dw |= q_e2m1(v.x) << (8 * row);
            dw |= q_e2m1(v.y) << (8 * row + 4);
        }
        d[col] = dw;
    }
    v4u e; e.x = d[0]; e.y = d[1]; e.z = d[2]; e.w = d[3];
    P[t] = e;
}

// ---------------- helpers ----------------
__device__ __forceinline__ void cr_weights(float t, float w[4]) {
    float u = t - floorf(t);
    float u2 = u * u, u3 = u2 * u;
    w[0] = -0.5f * u3 + u2 - 0.5f * u;
    w[1] =  1.5f * u3 - 2.5f * u2 + 1.0f;
    w[2] = -1.5f * u3 + 2.0f * u2 + 0.5f * u;
    w[3] =  0.5f * (u3 - u2);
}

// fp4-mag code (0..7) -> fp8 e4m3 byte LUT: [0,0.5,1,1.5,2,3,4,6]
//   = bytes [0x00,0x30,0x38,0x3C | 0x40,0x44,0x48,0x4C]
// v_perm selector 0-3 -> src1 bytes, 4-7 -> src0 bytes.
#define LUT_HI 0x4C484440u
#define LUT_LO 0x3C383000u

// One point: q = 4 dwords (cols 0..3), each byte r = (y<<4|x) of row r.
__device__ __forceinline__ float point_sqerr4(v4u q,
                                              const float wx[4], const float wy[4],
                                              float cx, float cy) {
    unsigned int d[4] = {q.x, q.y, q.z, q.w};
    float sx0 = 0.f, sx1 = 0.f, sx2 = 0.f, sx3 = 0.f;
    float sy0 = 0.f, sy1 = 0.f, sy2 = 0.f, sy3 = 0.f;
    #pragma unroll
    for (int col = 0; col < 4; ++col) {
        unsigned int dw = d[col];
        unsigned int xm = dw & 0x0F0F0F0Fu;
        unsigned int ym = (dw >> 4) & 0x0F0F0F0Fu;
        unsigned int fx = __builtin_amdgcn_perm(LUT_HI, LUT_LO, xm & 0x07070707u)
                          | ((xm & 0x08080808u) << 4);
        unsigned int fy = __builtin_amdgcn_perm(LUT_HI, LUT_LO, ym & 0x07070707u)
                          | ((ym & 0x08080808u) << 4);
        v2f x01 = __builtin_amdgcn_cvt_pk_f32_fp8((int)fx, false);
        v2f x23 = __builtin_amdgcn_cvt_pk_f32_fp8((int)fx, true);
        v2f y01 = __builtin_amdgcn_cvt_pk_f32_fp8((int)fy, false);
        v2f y23 = __builtin_amdgcn_cvt_pk_f32_fp8((int)fy, true);
        float wj = wy[col];
        sx0 = fmaf(wj, x01.x, sx0); sx1 = fmaf(wj, x01.y, sx1);
        sx2 = fmaf(wj, x23.x, sx2); sx3 = fmaf(wj, x23.y, sx3);
        sy0 = fmaf(wj, y01.x, sy0); sy1 = fmaf(wj, y01.y, sy1);
        sy2 = fmaf(wj, y23.x, sy2); sy3 = fmaf(wj, y23.y, sy3);
    }
    float mx = wx[0] * sx0; mx = fmaf(wx[1], sx1, mx);
    mx = fmaf(wx[2], sx2, mx); mx = fmaf(wx[3], sx3, mx);
    float my = wx[0] * sy0; my = fmaf(wx[1], sy1, my);
    my = fmaf(wx[2], sy2, my); my = fmaf(wx[3], sy3, my);
    float dx = cx - mx, dy = cy - my;
    return fmaf(dx, dx, dy * dy);
}

// ---------------- main kernel ----------------
// 4 consecutive points per thread: ONE 16B gather per point (1 aligned 64B
// line each), 6x16B coalesced streaming loads. All 10 loads pinned live by
// the asm fence -> forced MLP.
__global__ __launch_bounds__(256) void catmullrom_fp4_kernel(
    const v4f* __restrict__ ch1,     // (N/2) float4 = 2 points each
    const v4u* __restrict__ P,       // packed table, G*G x 16B
    const v4i* __restrict__ CP_idx,  // (N/2) int4 = 2 points each
    const v4f* __restrict__ r,       // (N/2) float4
    float* __restrict__ out,
    int N)
{
    const int tid = (int)threadIdx.x;
    const int g   = blockIdx.x * 256 + tid;
    const int nquads = (N + 3) >> 2;
    const int gg  = (g < nquads) ? g : (nquads - 1);   // clamped quad id
    const int b0  = 4 * g;                             // unclamped for tail scales

    const float s0 = (b0 + 0 < N && g < nquads) ? 1.f : 0.f;
    const float s1 = (b0 + 1 < N && g < nquads) ? 1.f : 0.f;
    const float s2 = (b0 + 2 < N && g < nquads) ? 1.f : 0.f;
    const float s3 = (b0 + 3 < N && g < nquads) ? 1.f : 0.f;

    // indices first (gathers depend on them); nt keeps the table L2-resident
    v4i i01 = __builtin_nontemporal_load(&CP_idx[2 * gg]);     // ix0,iy0,ix1,iy1
    v4i i23 = __builtin_nontemporal_load(&CP_idx[2 * gg + 1]); // ix2,iy2,ix3,iy3

    const int p0 = (i01.x - 1) * G + (i01.y - 1);
    const int p1 = (i01.z - 1) * G + (i01.w - 1);
    const int p2 = (i23.x - 1) * G + (i23.y - 1);
    const int p3 = (i23.z - 1) * G + (i23.w - 1);

    // 4 gathers (16B each, 16B-aligned -> exactly one 64B line per point)
    v4u q0 = P[p0], q1 = P[p1], q2 = P[p2], q3 = P[p3];

    v4f r01 = __builtin_nontemporal_load(&r[2 * gg]);
    v4f r23 = __builtin_nontemporal_load(&r[2 * gg + 1]);
    v4f c01 = __builtin_nontemporal_load(&ch1[2 * gg]);
    v4f c23 = __builtin_nontemporal_load(&ch1[2 * gg + 1]);

    // MLP fence: all 10 loads must be in flight simultaneously here.
    asm volatile(""
        : "+v"(q0), "+v"(q1), "+v"(q2), "+v"(q3),
          "+v"(i01), "+v"(i23),
          "+v"(r01), "+v"(r23), "+v"(c01), "+v"(c23));

    float acc = 0.0f;
    {
        float wx[4], wy[4];
        cr_weights(r01.x, wx); cr_weights(r01.y, wy);
        acc = fmaf(s0, point_sqerr4(q0, wx, wy, c01.x, c01.y), acc);
    }
    {
        float wx[4], wy[4];
        cr_weights(r01.z, wx); cr_weights(r01.w, wy);
        acc = fmaf(s1, point_sqerr4(q1, wx, wy, c01.z, c01.w), acc);
    }
    {
        float wx[4], wy[4];
        cr_weights(r23.x, wx); cr_weights(r23.y, wy);
        acc = fmaf(s2, point_sqerr4(q2, wx, wy, c23.x, c23.y), acc);
    }
    {
        float wx[4], wy[4];
        cr_weights(r23.z, wx); cr_weights(r23.w, wy);
        acc = fmaf(s3, point_sqerr4(q3, wx, wy, c23.z, c23.w), acc);
    }

    // ---- wave reduction + one atomic per block ----
    #pragma unroll
    for (int off = 32; off > 0; off >>= 1)
        acc += __shfl_down(acc, off, 64);

    __shared__ float wave_sums[4];
    const int lane = tid & 63;
    const int wid  = tid >> 6;
    if (lane == 0) wave_sums[wid] = acc;
    __syncthreads();
    if (tid == 0) {
        float s = wave_sums[0] + wave_sums[1] + wave_sums[2] + wave_sums[3];
        atomicAdd(out, s);
    }
}

extern "C" void kernel_launch(void* const* d_in, const int* in_sizes, int n_in,
                              void* d_out, int out_size, void* d_ws, size_t ws_size,
                              hipStream_t stream) {
    const v4f* ch1     = (const v4f*)d_in[0];
    const float2* CP   = (const float2*)d_in[1];
    const v4i* CP_idx  = (const v4i*)d_in[2];
    const v4f* r       = (const v4f*)d_in[3];
    float* out = (float*)d_out;

    const int N = in_sizes[0] / 2;  // ch1 is (N,2) floats

    v4u* P = (v4u*)d_ws;  // 4 MiB scratch
    pack_kernel<<<(G * G) / 256, 256, 0, stream>>>(CP, P, out);

    const int nquads = (N + 3) >> 2;
    const int blocks = (nquads + 255) / 256;
    catmullrom_fp4_kernel<<<blocks, 256, 0, stream>>>(ch1, P, CP_idx, r, out, N);
}

// Round 8
// 41.309 us; speedup vs baseline: 1.1909x; 1.1909x over previous
//
#include <hip/hip_runtime.h>

#define G 512

typedef float  v2f __attribute__((ext_vector_type(2)));
typedef float  v4f __attribute__((ext_vector_type(4)));
typedef int    v4i __attribute__((ext_vector_type(4)));
typedef unsigned int v4u __attribute__((ext_vector_type(4)));
// 16B vector with only 4B alignment guarantee (column window starts at any dword).
typedef unsigned int u4a4 __attribute__((ext_vector_type(4), aligned(4)));

// ---- fp4 e2m1 quantizer (round-to-nearest): |v| -> code 0..7, +8 for sign ----
// values: 0, 0.5, 1, 1.5, 2, 3, 4, 6 ; boundaries at 0.25,0.75,1.25,1.75,2.5,3.5,5
__device__ __forceinline__ unsigned int q_e2m1(float v) {
    float a = fabsf(v);
    unsigned int c = 0;
    c += (a >= 0.25f); c += (a >= 0.75f); c += (a >= 1.25f);
    c += (a >= 1.75f); c += (a >= 2.5f);  c += (a >= 3.5f);
    c += (a >= 5.0f);
    return c | (v < 0.0f ? 8u : 0u);
}

// ---------------- pack kernel ----------------
// P[i*G + j] = one dword: rows i..i+3 (clamped) of column j.
// byte[row] = (y_nibble<<4) | x_nibble, fp4 e2m1 each.
// Table = G*G*4B = 1 MiB. Also zeroes the output scalar.
__global__ __launch_bounds__(256) void pack_kernel(const float2* __restrict__ CP,
                                                   unsigned int* __restrict__ P,
                                                   float* __restrict__ out) {
    const int t = blockIdx.x * 256 + (int)threadIdx.x;  // [0, G*G)
    if (t == 0) *out = 0.0f;
    const int i = t >> 9;          // row-group anchor
    const int j = t & (G - 1);     // column
    unsigned int dw = 0;
    #pragma unroll
    for (int row = 0; row < 4; ++row) {
        float2 v = CP[(size_t)min(i + row, G - 1) * G + j];
        dw |= q_e2m1(v.x) << (8 * row);
        dw |= q_e2m1(v.y) << (8 * row + 4);
    }
    P[t] = dw;
}

// ---------------- helpers ----------------
__device__ __forceinline__ void cr_weights(float t, float w[4]) {
    float u = t - floorf(t);
    float u2 = u * u, u3 = u2 * u;
    w[0] = -0.5f * u3 + u2 - 0.5f * u;
    w[1] =  1.5f * u3 - 2.5f * u2 + 1.0f;
    w[2] = -1.5f * u3 + 2.0f * u2 + 0.5f * u;
    w[3] =  0.5f * (u3 - u2);
}

// fp4-mag code (0..7) -> fp8 e4m3 byte LUT: [0,0.5,1,1.5,2,3,4,6]
#define LUT_HI 0x4C484440u
#define LUT_LO 0x3C383000u

// One point: q = 4 dwords (cols 0..3 of the window), byte[row] = (y<<4|x).
__device__ __forceinline__ float point_sqerr4(u4a4 q,
                                              const float wx[4], const float wy[4],
                                              float cx, float cy) {
    unsigned int d[4] = {q.x, q.y, q.z, q.w};
    float sx0 = 0.f, sx1 = 0.f, sx2 = 0.f, sx3 = 0.f;
    float sy0 = 0.f, sy1 = 0.f, sy2 = 0.f, sy3 = 0.f;
    #pragma unroll
    for (int col = 0; col < 4; ++col) {
        unsigned int dw = d[col];
        unsigned int xm = dw & 0x0F0F0F0Fu;
        unsigned int ym = (dw >> 4) & 0x0F0F0F0Fu;
        unsigned int fx = __builtin_amdgcn_perm(LUT_HI, LUT_LO, xm & 0x07070707u)
                          | ((xm & 0x08080808u) << 4);
        unsigned int fy = __builtin_amdgcn_perm(LUT_HI, LUT_LO, ym & 0x07070707u)
                          | ((ym & 0x08080808u) << 4);
        v2f x01 = __builtin_amdgcn_cvt_pk_f32_fp8((int)fx, false);
        v2f x23 = __builtin_amdgcn_cvt_pk_f32_fp8((int)fx, true);
        v2f y01 = __builtin_amdgcn_cvt_pk_f32_fp8((int)fy, false);
        v2f y23 = __builtin_amdgcn_cvt_pk_f32_fp8((int)fy, true);
        float wj = wy[col];
        sx0 = fmaf(wj, x01.x, sx0); sx1 = fmaf(wj, x01.y, sx1);
        sx2 = fmaf(wj, x23.x, sx2); sx3 = fmaf(wj, x23.y, sx3);
        sy0 = fmaf(wj, y01.x, sy0); sy1 = fmaf(wj, y01.y, sy1);
        sy2 = fmaf(wj, y23.x, sy2); sy3 = fmaf(wj, y23.y, sy3);
    }
    float mx = wx[0] * sx0; mx = fmaf(wx[1], sx1, mx);
    mx = fmaf(wx[2], sx2, mx); mx = fmaf(wx[3], sx3, mx);
    float my = wx[0] * sy0; my = fmaf(wx[1], sy1, my);
    my = fmaf(wx[2], sy2, my); my = fmaf(wx[3], sy3, my);
    float dx = cx - mx, dy = cy - my;
    return fmaf(dx, dx, dy * dy);
}

// ---------------- main kernel ----------------
// 4 consecutive points per thread. Per point: ONE 16B gather (dwordx4, 4B
// aligned, ~1.2 cache lines avg) from the 1 MiB L2-resident table. 6x16B
// coalesced streaming loads. All loads pinned live by the asm fence.
__global__ __launch_bounds__(256) void catmullrom_fp4c_kernel(
    const v4f* __restrict__ ch1,     // (N/2) float4 = 2 points each
    const unsigned int* __restrict__ P,  // column-packed table, G*G dwords
    const v4i* __restrict__ CP_idx,  // (N/2) int4 = 2 points each
    const v4f* __restrict__ r,       // (N/2) float4
    float* __restrict__ out,
    int N)
{
    const int tid = (int)threadIdx.x;
    const int g   = blockIdx.x * 256 + tid;
    const int nquads = (N + 3) >> 2;
    const int gg  = (g < nquads) ? g : (nquads - 1);   // clamped quad id
    const int b0  = 4 * g;

    const float s0 = (b0 + 0 < N && g < nquads) ? 1.f : 0.f;
    const float s1 = (b0 + 1 < N && g < nquads) ? 1.f : 0.f;
    const float s2 = (b0 + 2 < N && g < nquads) ? 1.f : 0.f;
    const float s3 = (b0 + 3 < N && g < nquads) ? 1.f : 0.f;

    // indices first (gathers depend on them); nt keeps the table L2-resident
    v4i i01 = __builtin_nontemporal_load(&CP_idx[2 * gg]);     // ix0,iy0,ix1,iy1
    v4i i23 = __builtin_nontemporal_load(&CP_idx[2 * gg + 1]); // ix2,iy2,ix3,iy3

    const int p0 = (i01.x - 1) * G + (i01.y - 1);
    const int p1 = (i01.z - 1) * G + (i01.w - 1);
    const int p2 = (i23.x - 1) * G + (i23.y - 1);
    const int p3 = (i23.z - 1) * G + (i23.w - 1);

    // 4 gathers, one per point (16B window = cols jb..jb+3)
    u4a4 q0 = *(const u4a4*)(P + p0);
    u4a4 q1 = *(const u4a4*)(P + p1);
    u4a4 q2 = *(const u4a4*)(P + p2);
    u4a4 q3 = *(const u4a4*)(P + p3);

    v4f r01 = __builtin_nontemporal_load(&r[2 * gg]);
    v4f r23 = __builtin_nontemporal_load(&r[2 * gg + 1]);
    v4f c01 = __builtin_nontemporal_load(&ch1[2 * gg]);
    v4f c23 = __builtin_nontemporal_load(&ch1[2 * gg + 1]);

    // MLP fence: all loads must be in flight simultaneously here.
    asm volatile(""
        : "+v"(q0), "+v"(q1), "+v"(q2), "+v"(q3),
          "+v"(i01), "+v"(i23),
          "+v"(r01), "+v"(r23), "+v"(c01), "+v"(c23));

    float acc = 0.0f;
    {
        float wx[4], wy[4];
        cr_weights(r01.x, wx); cr_weights(r01.y, wy);
        acc = fmaf(s0, point_sqerr4(q0, wx, wy, c01.x, c01.y), acc);
    }
    {
        float wx[4], wy[4];
        cr_weights(r01.z, wx); cr_weights(r01.w, wy);
        acc = fmaf(s1, point_sqerr4(q1, wx, wy, c01.z, c01.w), acc);
    }
    {
        float wx[4], wy[4];
        cr_weights(r23.x, wx); cr_weights(r23.y, wy);
        acc = fmaf(s2, point_sqerr4(q2, wx, wy, c23.x, c23.y), acc);
    }
    {
        float wx[4], wy[4];
        cr_weights(r23.z, wx); cr_weights(r23.w, wy);
        acc = fmaf(s3, point_sqerr4(q3, wx, wy, c23.z, c23.w), acc);
    }

    // ---- wave reduction + one atomic per block ----
    #pragma unroll
    for (int off = 32; off > 0; off >>= 1)
        acc += __shfl_down(acc, off, 64);

    __shared__ float wave_sums[4];
    const int lane = tid & 63;
    const int wid  = tid >> 6;
    if (lane == 0) wave_sums[wid] = acc;
    __syncthreads();
    if (tid == 0) {
        float s = wave_sums[0] + wave_sums[1] + wave_sums[2] + wave_sums[3];
        atomicAdd(out, s);
    }
}

extern "C" void kernel_launch(void* const* d_in, const int* in_sizes, int n_in,
                              void* d_out, int out_size, void* d_ws, size_t ws_size,
                              hipStream_t stream) {
    const v4f* ch1     = (const v4f*)d_in[0];
    const float2* CP   = (const float2*)d_in[1];
    const v4i* CP_idx  = (const v4i*)d_in[2];
    const v4f* r       = (const v4f*)d_in[3];
    float* out = (float*)d_out;

    const int N = in_sizes[0] / 2;  // ch1 is (N,2) floats

    unsigned int* P = (unsigned int*)d_ws;  // 1 MiB scratch
    pack_kernel<<<(G * G) / 256, 256, 0, stream>>>(CP, P, out);

    const int nquads = (N + 3) >> 2;
    const int blocks = (nquads + 255) / 256;
    catmullrom_fp4c_kernel<<<blocks, 256, 0, stream>>>(ch1, P, CP_idx, r, out, N);
}